// Round 1
// baseline (158.815 us; speedup 1.0000x reference)
//
#include <hip/hip_runtime.h>

typedef __bf16 bf16x8 __attribute__((ext_vector_type(8)));
typedef float f32x4 __attribute__((ext_vector_type(4)));
typedef unsigned short u16;
typedef unsigned short u16x8 __attribute__((ext_vector_type(8)));
typedef unsigned short u16x4 __attribute__((ext_vector_type(4)));

#define MFMA16(a, b, c) __builtin_amdgcn_mfma_f32_16x16x32_bf16(a, b, c, 0, 0, 0)

__device__ __forceinline__ u16 f2bf(float f) {
    unsigned u = __builtin_bit_cast(unsigned, f);
    u += 0x7fffu + ((u >> 16) & 1u);   // RNE
    return (u16)(u >> 16);
}

__device__ __forceinline__ bf16x8 ld_frag(const u16* p) {
    u16x8 v = *(const u16x8*)p;
    return __builtin_bit_cast(bf16x8, v);
}

// ---------------------------------------------------------------------------
// Kernel 1: q/k/v = x @ W^T + b, output bf16 [16384][128].
// grid (3, 128): x=which of {Wq,Wk,Wv}, y=128-row M-tile. BK=32, 256 thr.
// Both x and W are K-contiguous -> contiguous b128 fragment loads from LDS.
// ---------------------------------------------------------------------------
__global__ __launch_bounds__(256) void qkv_proj(
    const float* __restrict__ x,
    const float* __restrict__ Wq, const float* __restrict__ bq,
    const float* __restrict__ Wk, const float* __restrict__ bk,
    const float* __restrict__ Wv, const float* __restrict__ bv,
    u16* __restrict__ qo, u16* __restrict__ ko, u16* __restrict__ vo)
{
    constexpr int LDT = 40;  // 32 + 8 pad (16B) -> rows 80B: 16B-aligned, bank-safe
    __shared__ __align__(16) u16 aL[128 * LDT];
    __shared__ __align__(16) u16 bL[128 * LDT];

    const int sel = blockIdx.x;
    const int m0  = blockIdx.y * 128;
    const float* W    = sel == 0 ? Wq : (sel == 1 ? Wk : Wv);
    const float* bias = sel == 0 ? bq : (sel == 1 ? bk : bv);
    u16* out          = sel == 0 ? qo : (sel == 1 ? ko : vo);

    const int tid  = threadIdx.x;
    const int lane = tid & 63;
    const int w    = tid >> 6;
    const int quad = lane >> 4, l16 = lane & 15;
    const int wm = (w >> 1) * 64, wn = (w & 1) * 64;

    f32x4 acc[4][4] = {};

    for (int kk = 0; kk < 1024; kk += 32) {
        if (kk) __syncthreads();
        // stage A (x tile, fp32->bf16) and B (W tile, fp32->bf16): 128x32 each
        #pragma unroll
        for (int i = 0; i < 4; ++i) {
            int slot = tid + i * 256;
            int row = slot >> 3, c4 = (slot & 7) * 4;
            float4 av  = *(const float4*)(x + (size_t)(m0 + row) * 1024 + kk + c4);
            float4 bv4 = *(const float4*)(W + (size_t)row * 1024 + kk + c4);
            u16x4 ap = { f2bf(av.x), f2bf(av.y), f2bf(av.z), f2bf(av.w) };
            u16x4 bp = { f2bf(bv4.x), f2bf(bv4.y), f2bf(bv4.z), f2bf(bv4.w) };
            *(u16x4*)&aL[row * LDT + c4] = ap;
            *(u16x4*)&bL[row * LDT + c4] = bp;
        }
        __syncthreads();

        bf16x8 af[4], bfr[4];
        #pragma unroll
        for (int mi = 0; mi < 4; ++mi)
            af[mi] = ld_frag(&aL[(wm + mi * 16 + l16) * LDT + quad * 8]);
        #pragma unroll
        for (int ni = 0; ni < 4; ++ni)
            bfr[ni] = ld_frag(&bL[(wn + ni * 16 + l16) * LDT + quad * 8]);
        #pragma unroll
        for (int mi = 0; mi < 4; ++mi)
            #pragma unroll
            for (int ni = 0; ni < 4; ++ni)
                acc[mi][ni] = MFMA16(af[mi], bfr[ni], acc[mi][ni]);
    }

    // epilogue: + bias, cvt bf16, store. C/D: col=l16, row=quad*4+r (m89/m91)
    #pragma unroll
    for (int ni = 0; ni < 4; ++ni) {
        int col = wn + ni * 16 + l16;
        float bb = bias[col];
        #pragma unroll
        for (int mi = 0; mi < 4; ++mi)
            #pragma unroll
            for (int r = 0; r < 4; ++r) {
                int rowg = m0 + wm + mi * 16 + quad * 4 + r;
                out[(size_t)rowg * 128 + col] = f2bf(acc[mi][ni][r] + bb);
            }
    }
}

// ---------------------------------------------------------------------------
// Kernel 2: partial Tt[e][d] = sum_t v[t][e]*k[t][d] over a 128-t chunk.
// grid (32, 4): x=chunk, y=batch. Both operands transposed into LDS (t-minor).
// ---------------------------------------------------------------------------
__global__ __launch_bounds__(256) void kt_v(
    const u16* __restrict__ ko, const u16* __restrict__ vo,
    float* __restrict__ part)
{
    constexpr int LDT = 40;
    __shared__ __align__(16) u16 vT[128 * LDT];  // [e][t]
    __shared__ __align__(16) u16 kT[128 * LDT];  // [d][t]

    const int c = blockIdx.x;          // 0..31
    const int b = blockIdx.y;          // 0..3
    const int t0 = c * 128;
    const int tid  = threadIdx.x;
    const int lane = tid & 63, w = tid >> 6;
    const int quad = lane >> 4, l16 = lane & 15;
    const int we = (w >> 1) * 64, wd = (w & 1) * 64;

    f32x4 acc[4][4] = {};

    for (int ts = 0; ts < 128; ts += 32) {
        if (ts) __syncthreads();
        // stage 32x128 of k and v, transposed: lane map t=tid&31 keeps LDS
        // write banks spread (consecutive t -> consecutive byte addresses)
        #pragma unroll
        for (int i = 0; i < 2; ++i) {
            int tloc = tid & 31;
            int e8 = ((tid >> 5) + i * 8) * 8;
            size_t gr = (size_t)(b * 4096 + t0 + ts + tloc) * 128 + e8;
            u16x8 gv = *(const u16x8*)(vo + gr);
            u16x8 gk = *(const u16x8*)(ko + gr);
            #pragma unroll
            for (int j = 0; j < 8; ++j) {
                vT[(e8 + j) * LDT + tloc] = gv[j];
                kT[(e8 + j) * LDT + tloc] = gk[j];
            }
        }
        __syncthreads();

        bf16x8 af[4], bfr[4];
        #pragma unroll
        for (int mi = 0; mi < 4; ++mi)
            af[mi] = ld_frag(&vT[(we + mi * 16 + l16) * LDT + quad * 8]);
        #pragma unroll
        for (int ni = 0; ni < 4; ++ni)
            bfr[ni] = ld_frag(&kT[(wd + ni * 16 + l16) * LDT + quad * 8]);
        #pragma unroll
        for (int mi = 0; mi < 4; ++mi)
            #pragma unroll
            for (int ni = 0; ni < 4; ++ni)
                acc[mi][ni] = MFMA16(af[mi], bfr[ni], acc[mi][ni]);
    }

    float* dst = part + (size_t)(b * 32 + c) * 16384;
    #pragma unroll
    for (int mi = 0; mi < 4; ++mi)
        #pragma unroll
        for (int ni = 0; ni < 4; ++ni)
            #pragma unroll
            for (int r = 0; r < 4; ++r)
                dst[(we + mi * 16 + quad * 4 + r) * 128 + (wd + ni * 16 + l16)] =
                    acc[mi][ni][r];
}

// ---------------------------------------------------------------------------
// Kernel 2b: reduce 32 fp32 partials -> Tt bf16 [4][128][128]
// ---------------------------------------------------------------------------
__global__ __launch_bounds__(256) void reduceT(
    const float* __restrict__ part, u16* __restrict__ T)
{
    int gid = blockIdx.x * 256 + threadIdx.x;   // 0..65535
    int b = gid >> 14, idx = gid & 16383;
    const float* p = part + (size_t)b * 32 * 16384 + idx;
    float s = 0.f;
    #pragma unroll
    for (int c = 0; c < 32; ++c) s += p[(size_t)c * 16384];
    T[gid] = f2bf(s);
}

// ---------------------------------------------------------------------------
// Kernel 3: out[s][e] = scale * sum_d q[s][d] * Tt[e][d]   (K=128)
// grid (256): 64-row M-tiles. Tt is stored [e][d] so B-frags are d-contiguous.
// ---------------------------------------------------------------------------
__global__ __launch_bounds__(256) void out_gemm(
    const u16* __restrict__ qo, const u16* __restrict__ T,
    float* __restrict__ out)
{
    constexpr int LDQ = 136;  // 128 + 8 pad
    __shared__ __align__(16) u16 qL[64 * LDQ];
    __shared__ __align__(16) u16 tL[128 * LDQ];

    const int s0 = blockIdx.x * 64;
    const int b  = s0 >> 12;
    const int tid  = threadIdx.x;
    const int lane = tid & 63, w = tid >> 6;
    const int quad = lane >> 4, l16 = lane & 15;
    const int wm = (w >> 1) * 32, wn = (w & 1) * 64;

    #pragma unroll
    for (int i = 0; i < 4; ++i) {
        int slot = tid + i * 256;
        int row = slot >> 4, c8 = (slot & 15) * 8;
        *(u16x8*)&qL[row * LDQ + c8] =
            *(const u16x8*)(qo + (size_t)(s0 + row) * 128 + c8);
    }
    #pragma unroll
    for (int i = 0; i < 8; ++i) {
        int slot = tid + i * 256;
        int row = slot >> 4, c8 = (slot & 15) * 8;
        *(u16x8*)&tL[row * LDQ + c8] =
            *(const u16x8*)(T + (size_t)b * 16384 + row * 128 + c8);
    }
    __syncthreads();

    f32x4 acc[2][4] = {};
    #pragma unroll
    for (int ks = 0; ks < 128; ks += 32) {
        bf16x8 af[2], bfr[4];
        #pragma unroll
        for (int mi = 0; mi < 2; ++mi)
            af[mi] = ld_frag(&qL[(wm + mi * 16 + l16) * LDQ + ks + quad * 8]);
        #pragma unroll
        for (int ni = 0; ni < 4; ++ni)
            bfr[ni] = ld_frag(&tL[(wn + ni * 16 + l16) * LDQ + ks + quad * 8]);
        #pragma unroll
        for (int mi = 0; mi < 2; ++mi)
            #pragma unroll
            for (int ni = 0; ni < 4; ++ni)
                acc[mi][ni] = MFMA16(af[mi], bfr[ni], acc[mi][ni]);
    }

    const float scale = 0.088388347648318447f;  // 128^-0.5
    #pragma unroll
    for (int mi = 0; mi < 2; ++mi)
        #pragma unroll
        for (int ni = 0; ni < 4; ++ni)
            #pragma unroll
            for (int r = 0; r < 4; ++r)
                out[(size_t)(s0 + wm + mi * 16 + quad * 4 + r) * 128 +
                    wn + ni * 16 + l16] = scale * acc[mi][ni][r];
}

// ---------------------------------------------------------------------------
extern "C" void kernel_launch(void* const* d_in, const int* in_sizes, int n_in,
                              void* d_out, int out_size, void* d_ws, size_t ws_size,
                              hipStream_t stream)
{
    const float* x  = (const float*)d_in[0];
    const float* Wq = (const float*)d_in[1];
    const float* bq = (const float*)d_in[2];
    const float* Wk = (const float*)d_in[3];
    const float* bk = (const float*)d_in[4];
    const float* Wv = (const float*)d_in[5];
    const float* bv = (const float*)d_in[6];
    float* out = (float*)d_out;

    char* ws = (char*)d_ws;
    u16*   qo   = (u16*)(ws);                          //  4 MB
    u16*   ko   = (u16*)(ws + ((size_t)4 << 20));      //  4 MB
    u16*   vo   = (u16*)(ws + ((size_t)8 << 20));      //  4 MB
    float* part = (float*)(ws + ((size_t)12 << 20));   //  8 MB
    u16*   T    = (u16*)(ws + ((size_t)20 << 20));     // 128 KB

    hipLaunchKernelGGL(qkv_proj, dim3(3, 128), dim3(256), 0, stream,
                       x, Wq, bq, Wk, bk, Wv, bv, qo, ko, vo);
    hipLaunchKernelGGL(kt_v, dim3(32, 4), dim3(256), 0, stream, ko, vo, part);
    hipLaunchKernelGGL(reduceT, dim3(256), dim3(256), 0, stream, part, T);
    hipLaunchKernelGGL(out_gemm, dim3(256), dim3(256), 0, stream, qo, T, out);
}

// Round 2
// 155.082 us; speedup vs baseline: 1.0241x; 1.0241x over previous
//
#include <hip/hip_runtime.h>

typedef __bf16 bf16x8 __attribute__((ext_vector_type(8)));
typedef float f32x4 __attribute__((ext_vector_type(4)));
typedef float f32x16 __attribute__((ext_vector_type(16)));
typedef unsigned short u16;
typedef unsigned short u16x8 __attribute__((ext_vector_type(8)));

#define MFMA16(a, b, c) __builtin_amdgcn_mfma_f32_16x16x32_bf16(a, b, c, 0, 0, 0)
#define MFMA32(a, b, c) __builtin_amdgcn_mfma_f32_32x32x16_bf16(a, b, c, 0, 0, 0)

__device__ __forceinline__ u16 f2bf(float f) {
    unsigned u = __builtin_bit_cast(unsigned, f);
    u += 0x7fffu + ((u >> 16) & 1u);   // RNE
    return (u16)(u >> 16);
}

__device__ __forceinline__ bf16x8 ld_frag(const u16* p) {
    u16x8 v = *(const u16x8*)p;
    return __builtin_bit_cast(bf16x8, v);
}

// async global->LDS, 16B per lane; LDS dest = uniform base + lane*16
__device__ __forceinline__ void glds16(const void* g, void* l) {
    __builtin_amdgcn_global_load_lds(
        (const __attribute__((address_space(1))) unsigned int*)g,
        (__attribute__((address_space(3))) unsigned int*)l, 16, 0, 0);
}

// ---------------------------------------------------------------------------
// wcvt: pre-convert Wq|Wk|Wv (fp32, [128][1024] each) into bf16 in MFMA
// B-fragment order: Wb[((c*24 + NB*2 + ks)*64 + l)*8 + j] =
//   W[NB*32 + (l&31)][c*32 + ks*16 + (l>>5)*8 + j]
// so qkv can global_load_lds identity-copy 1KB sub-blocks.
// ---------------------------------------------------------------------------
__global__ __launch_bounds__(256) void wcvt(
    const float* __restrict__ Wq, const float* __restrict__ Wk,
    const float* __restrict__ Wv, u16* __restrict__ Wb)
{
    int g = blockIdx.x * 256 + threadIdx.x;      // 49152 threads
    int l = g & 63;
    int rest = g >> 6;                           // c*24 + nb*2 + ks
    int ks = rest & 1;
    int nb = (rest >> 1) % 12;
    int c  = (rest >> 1) / 12;
    int n  = nb * 32 + (l & 31);
    int k0 = c * 32 + ks * 16 + (l >> 5) * 8;
    const float* W = n < 128 ? Wq + (size_t)n * 1024
                   : n < 256 ? Wk + (size_t)(n - 128) * 1024
                             : Wv + (size_t)(n - 256) * 1024;
    float4 a = *(const float4*)(W + k0);
    float4 b = *(const float4*)(W + k0 + 4);
    u16x8 o = { f2bf(a.x), f2bf(a.y), f2bf(a.z), f2bf(a.w),
                f2bf(b.x), f2bf(b.y), f2bf(b.z), f2bf(b.w) };
    *(u16x8*)(Wb + (size_t)g * 8) = o;
}

// ---------------------------------------------------------------------------
// qkv_fused: [16384][1024] fp32 x  @  [384][1024] W^T + bias -> q|k|v bf16.
// grid 256 (M-tile 64), 256 thr / 4 waves. Wave tile 64x96, 32x32x16 MFMA.
// Double-buffered LDS; W via global_load_lds (bf16 pre-converted, frag order);
// x converted in-flight and written in frag order (identity ds ops, no pad).
// ---------------------------------------------------------------------------
__global__ __launch_bounds__(256, 2) void qkv_fused(
    const float* __restrict__ x, const u16* __restrict__ Wb,
    const float* __restrict__ bq, const float* __restrict__ bk,
    const float* __restrict__ bv,
    u16* __restrict__ qo, u16* __restrict__ ko, u16* __restrict__ vo)
{
    __shared__ __align__(16) u16 As[2][2048];    //  4 KB per buf
    __shared__ __align__(16) u16 Bs[2][12288];   // 24 KB per buf

    const int m0 = blockIdx.x * 64;
    const int tid = threadIdx.x, lane = tid & 63, w = tid >> 6;

    // A staging: wave w produces A-frag f=w (mb=w>>1, ks=w&1)
    const int arow = m0 + (w >> 1) * 32 + (lane & 31);
    const int acol = (w & 1) * 16 + (lane >> 5) * 8;
    const float* xp = x + (size_t)arow * 1024 + acol;

    // W staging: wave w identity-copies sub-blocks w*6 .. w*6+5 of each chunk
    const u16* wsrc = Wb + (size_t)(w * 6) * 512 + lane * 8;

    f32x16 acc[2][3] = {};

    // prologue: stage chunk 0 -> buf 0
    {
        #pragma unroll
        for (int j = 0; j < 6; ++j)
            glds16(wsrc + j * 512, &Bs[0][(w * 6 + j) * 512]);
        float4 xa = *(const float4*)(xp);
        float4 xb = *(const float4*)(xp + 4);
        u16x8 o = { f2bf(xa.x), f2bf(xa.y), f2bf(xa.z), f2bf(xa.w),
                    f2bf(xb.x), f2bf(xb.y), f2bf(xb.z), f2bf(xb.w) };
        *(u16x8*)&As[0][tid * 8] = o;
    }

    for (int c = 0; c < 32; ++c) {
        const int cur = c & 1, nxt = cur ^ 1;
        __syncthreads();                      // buf[cur] staged for all waves
        float4 xa, xb;
        const bool pf = (c < 31);
        if (pf) {                             // issue next-chunk loads FIRST
            const u16* ws2 = wsrc + (size_t)(c + 1) * 12288;
            #pragma unroll
            for (int j = 0; j < 6; ++j)
                glds16(ws2 + j * 512, &Bs[nxt][(w * 6 + j) * 512]);
            xa = *(const float4*)(xp + (c + 1) * 32);
            xb = *(const float4*)(xp + (c + 1) * 32 + 4);
        }
        // compute chunk c
        bf16x8 af[2][2], bfr[3][2];
        #pragma unroll
        for (int mb = 0; mb < 2; ++mb)
            #pragma unroll
            for (int ks = 0; ks < 2; ++ks)
                af[mb][ks] = ld_frag(&As[cur][(mb * 2 + ks) * 512 + lane * 8]);
        #pragma unroll
        for (int nb = 0; nb < 3; ++nb)
            #pragma unroll
            for (int ks = 0; ks < 2; ++ks)
                bfr[nb][ks] = ld_frag(&Bs[cur][((w * 3 + nb) * 2 + ks) * 512 + lane * 8]);
        #pragma unroll
        for (int ks = 0; ks < 2; ++ks)
            #pragma unroll
            for (int mb = 0; mb < 2; ++mb)
                #pragma unroll
                for (int nb = 0; nb < 3; ++nb)
                    acc[mb][nb] = MFMA32(af[mb][ks], bfr[nb][ks], acc[mb][nb]);
        if (pf) {
            u16x8 o = { f2bf(xa.x), f2bf(xa.y), f2bf(xa.z), f2bf(xa.w),
                        f2bf(xb.x), f2bf(xb.y), f2bf(xb.z), f2bf(xb.w) };
            *(u16x8*)&As[nxt][tid * 8] = o;
        }
    }

    // epilogue: +bias, bf16, store. 32x32 C/D: col=lane&31,
    // row=(r&3)+8*(r>>2)+4*(lane>>5)  [m74/m101]
    #pragma unroll
    for (int nb = 0; nb < 3; ++nb) {
        int ng = w * 96 + nb * 32 + (lane & 31);
        int sel = ng >> 7, col = ng & 127;
        const float* bias = sel == 0 ? bq : (sel == 1 ? bk : bv);
        u16* out          = sel == 0 ? qo : (sel == 1 ? ko : vo);
        float bb = bias[col];
        #pragma unroll
        for (int mb = 0; mb < 2; ++mb)
            #pragma unroll
            for (int r = 0; r < 16; ++r) {
                int row = m0 + mb * 32 + (r & 3) + 8 * (r >> 2) + 4 * (lane >> 5);
                out[(size_t)row * 128 + col] = f2bf(acc[mb][nb][r] + bb);
            }
    }
}

// ---------------------------------------------------------------------------
// kt_v: partial Tt[e][d] = sum_t v[t][e]*k[t][d] over 128-t chunk.
// grid (32,4). Vectorized loads, transposed scatter into 136-padded LDS
// (row stride 272B -> 2-way bank alias = free).
// ---------------------------------------------------------------------------
__global__ __launch_bounds__(256) void kt_v(
    const u16* __restrict__ ko, const u16* __restrict__ vo,
    float* __restrict__ part)
{
    constexpr int LDT = 136;
    __shared__ __align__(16) u16 vT[128 * LDT];
    __shared__ __align__(16) u16 kT[128 * LDT];

    const int c = blockIdx.x, b = blockIdx.y;
    const int t0 = c * 128;
    const int tid = threadIdx.x, lane = tid & 63, w = tid >> 6;
    const int quad = lane >> 4, l16 = lane & 15;
    const int we = (w >> 1) * 64, wd = (w & 1) * 64;
    const int tl = tid & 63, eg = tid >> 6;

    #pragma unroll
    for (int ts = 0; ts < 128; ts += 64)
        #pragma unroll
        for (int i = 0; i < 4; ++i) {
            int e8 = (eg + i * 4) * 8;
            size_t gr = (size_t)(b * 4096 + t0 + ts + tl) * 128 + e8;
            u16x8 gv = *(const u16x8*)(vo + gr);
            u16x8 gk = *(const u16x8*)(ko + gr);
            #pragma unroll
            for (int j = 0; j < 8; ++j) {
                vT[(e8 + j) * LDT + ts + tl] = gv[j];
                kT[(e8 + j) * LDT + ts + tl] = gk[j];
            }
        }
    __syncthreads();

    f32x4 acc[4][4] = {};
    #pragma unroll
    for (int ks = 0; ks < 4; ++ks) {
        bf16x8 af[4], bfr[4];
        #pragma unroll
        for (int mi = 0; mi < 4; ++mi)
            af[mi] = ld_frag(&vT[(we + mi * 16 + l16) * LDT + ks * 32 + quad * 8]);
        #pragma unroll
        for (int ni = 0; ni < 4; ++ni)
            bfr[ni] = ld_frag(&kT[(wd + ni * 16 + l16) * LDT + ks * 32 + quad * 8]);
        #pragma unroll
        for (int mi = 0; mi < 4; ++mi)
            #pragma unroll
            for (int ni = 0; ni < 4; ++ni)
                acc[mi][ni] = MFMA16(af[mi], bfr[ni], acc[mi][ni]);
    }

    float* dst = part + (size_t)(b * 32 + c) * 16384;
    #pragma unroll
    for (int mi = 0; mi < 4; ++mi)
        #pragma unroll
        for (int ni = 0; ni < 4; ++ni)
            #pragma unroll
            for (int r = 0; r < 4; ++r)
                dst[(we + mi * 16 + quad * 4 + r) * 128 + (wd + ni * 16 + l16)] =
                    acc[mi][ni][r];
}

// ---------------------------------------------------------------------------
// reduceT: 32 fp32 partials -> Tt bf16 [4][128][128]
// ---------------------------------------------------------------------------
__global__ __launch_bounds__(256) void reduceT(
    const float* __restrict__ part, u16* __restrict__ T)
{
    int gid = blockIdx.x * 256 + threadIdx.x;   // 0..65535
    int b = gid >> 14, idx = gid & 16383;
    const float* p = part + (size_t)b * 32 * 16384 + idx;
    float s = 0.f;
    #pragma unroll
    for (int c = 0; c < 32; ++c) s += p[(size_t)c * 16384];
    T[gid] = f2bf(s);
}

// ---------------------------------------------------------------------------
// out_gemm: out[s][e] = scale * sum_d q[s][d] * Tt[e][d]   (K=128)
// ---------------------------------------------------------------------------
__global__ __launch_bounds__(256) void out_gemm(
    const u16* __restrict__ qo, const u16* __restrict__ T,
    float* __restrict__ out)
{
    constexpr int LDQ = 136;
    __shared__ __align__(16) u16 qL[64 * LDQ];
    __shared__ __align__(16) u16 tL[128 * LDQ];

    const int s0 = blockIdx.x * 64;
    const int b  = s0 >> 12;
    const int tid = threadIdx.x;
    const int lane = tid & 63, w = tid >> 6;
    const int quad = lane >> 4, l16 = lane & 15;
    const int wm = (w >> 1) * 32, wn = (w & 1) * 64;

    #pragma unroll
    for (int i = 0; i < 4; ++i) {
        int slot = tid + i * 256;
        int row = slot >> 4, c8 = (slot & 15) * 8;
        *(u16x8*)&qL[row * LDQ + c8] =
            *(const u16x8*)(qo + (size_t)(s0 + row) * 128 + c8);
    }
    #pragma unroll
    for (int i = 0; i < 8; ++i) {
        int slot = tid + i * 256;
        int row = slot >> 4, c8 = (slot & 15) * 8;
        *(u16x8*)&tL[row * LDQ + c8] =
            *(const u16x8*)(T + (size_t)b * 16384 + row * 128 + c8);
    }
    __syncthreads();

    f32x4 acc[2][4] = {};
    #pragma unroll
    for (int ks = 0; ks < 128; ks += 32) {
        bf16x8 af[2], bfr[4];
        #pragma unroll
        for (int mi = 0; mi < 2; ++mi)
            af[mi] = ld_frag(&qL[(wm + mi * 16 + l16) * LDQ + ks + quad * 8]);
        #pragma unroll
        for (int ni = 0; ni < 4; ++ni)
            bfr[ni] = ld_frag(&tL[(wn + ni * 16 + l16) * LDQ + ks + quad * 8]);
        #pragma unroll
        for (int mi = 0; mi < 2; ++mi)
            #pragma unroll
            for (int ni = 0; ni < 4; ++ni)
                acc[mi][ni] = MFMA16(af[mi], bfr[ni], acc[mi][ni]);
    }

    const float scale = 0.088388347648318447f;  // 128^-0.5
    #pragma unroll
    for (int mi = 0; mi < 2; ++mi)
        #pragma unroll
        for (int ni = 0; ni < 4; ++ni)
            #pragma unroll
            for (int r = 0; r < 4; ++r)
                out[(size_t)(s0 + wm + mi * 16 + quad * 4 + r) * 128 +
                    wn + ni * 16 + l16] = scale * acc[mi][ni][r];
}

// ---------------------------------------------------------------------------
extern "C" void kernel_launch(void* const* d_in, const int* in_sizes, int n_in,
                              void* d_out, int out_size, void* d_ws, size_t ws_size,
                              hipStream_t stream)
{
    const float* x  = (const float*)d_in[0];
    const float* Wq = (const float*)d_in[1];
    const float* bq = (const float*)d_in[2];
    const float* Wk = (const float*)d_in[3];
    const float* bk = (const float*)d_in[4];
    const float* Wv = (const float*)d_in[5];
    const float* bv = (const float*)d_in[6];
    float* out = (float*)d_out;

    char* ws = (char*)d_ws;
    u16*   qo   = (u16*)(ws);                          //  4 MB
    u16*   ko   = (u16*)(ws + ((size_t)4 << 20));      //  4 MB
    u16*   vo   = (u16*)(ws + ((size_t)8 << 20));      //  4 MB
    // Wb (768 KB) and part (8 MB) alias: Wb is dead before kt_v writes part.
    u16*   Wb   = (u16*)(ws + ((size_t)12 << 20));
    float* part = (float*)(ws + ((size_t)12 << 20));
    u16*   T    = (u16*)(ws + ((size_t)20 << 20));     // 128 KB

    hipLaunchKernelGGL(wcvt, dim3(192), dim3(256), 0, stream, Wq, Wk, Wv, Wb);
    hipLaunchKernelGGL(qkv_fused, dim3(256), dim3(256), 0, stream,
                       x, Wb, bq, bk, bv, qo, ko, vo);
    hipLaunchKernelGGL(kt_v, dim3(32, 4), dim3(256), 0, stream, ko, vo, part);
    hipLaunchKernelGGL(reduceT, dim3(256), dim3(256), 0, stream, part, T);
    hipLaunchKernelGGL(out_gemm, dim3(256), dim3(256), 0, stream, qo, T, out);
}